// Round 11
// baseline (830.959 us; speedup 1.0000x reference)
//
#include <hip/hip_runtime.h>
#include <hip/hip_bf16.h>

#define SQ 2048
#define SK 2048
#define DD 128
#define NBH 32
#define QBLK 64
#define KBLK 32
#define NKT (SK / KBLK)
#define SCALE 0.20884964425119185f
#define SCL2 (SCALE * 1.4426950408889634f)   // fold log2(e): exp2

typedef __attribute__((ext_vector_type(8))) short short8;
typedef __attribute__((ext_vector_type(4))) float f32x4;
typedef __attribute__((ext_vector_type(4))) unsigned int u32x4;

// bf16 path LDS: swizzled K-image, double-buffered (2 x 8 KB)
#define KIMG 8192
#define SMEM_BF 16384
// f32 fallback LDS (R9-proven layout)
#define KPITCH 272
#define VPITCH 80
#define VOFF_F 8704
#define SMEM_F32 18944

#define GLDS(G, L) __builtin_amdgcn_global_load_lds( \
    (const __attribute__((address_space(1))) unsigned int*)(G), \
    (__attribute__((address_space(3))) unsigned int*)(L), 16, 0, 0)

static __device__ __forceinline__ unsigned int pk_bf16(float lo, float hi) {
    float2 f2; f2.x = lo; f2.y = hi;
    __hip_bfloat162 h = __float22bfloat162_rn(f2);   // v_cvt_pk_bf16_f32
    union { __hip_bfloat162 h2; unsigned int u; } cv; cv.h2 = h;
    return cv.u;
}
static __device__ __forceinline__ unsigned short f2bf(float f) {
    unsigned int u = __float_as_uint(f);
    u = u + 0x7fffu + ((u >> 16) & 1u);              // RNE (matches cvt_pk)
    return (unsigned short)(u >> 16);
}

// softmax + bf16 pack + shfl-redistribute into PV A-operand layout (R3..R9-proven)
#define SOFTMAX_PACK(PA, SA_, SB_, MCa, MCb, LPART)                            \
  { float p_[8];                                                               \
    p_[0] = __builtin_amdgcn_exp2f(SA_[0]*SCL2);                               \
    p_[1] = __builtin_amdgcn_exp2f(SA_[1]*SCL2);                               \
    p_[2] = __builtin_amdgcn_exp2f(SA_[2]*SCL2);                               \
    p_[3] = __builtin_amdgcn_exp2f(SA_[3]*SCL2);                               \
    p_[4] = __builtin_amdgcn_exp2f(SB_[0]*SCL2);                               \
    p_[5] = __builtin_amdgcn_exp2f(SB_[1]*SCL2);                               \
    p_[6] = __builtin_amdgcn_exp2f(SB_[2]*SCL2);                               \
    p_[7] = __builtin_amdgcn_exp2f(SB_[3]*SCL2);                               \
    LPART += ((p_[0]+p_[1]) + (p_[2]+p_[3])) + ((p_[4]+p_[5]) + (p_[6]+p_[7]));\
    p_[0]*=MCa.x; p_[1]*=MCa.y; p_[2]*=MCa.z; p_[3]*=MCa.w;                    \
    p_[4]*=MCb.x; p_[5]*=MCb.y; p_[6]*=MCb.z; p_[7]*=MCb.w;                    \
    unsigned int P0 = pk_bf16(p_[0],p_[1]), P1 = pk_bf16(p_[2],p_[3]);         \
    unsigned int P2 = pk_bf16(p_[4],p_[5]), P3 = pk_bf16(p_[6],p_[7]);         \
    unsigned int a0 = __shfl((int)P0, sA), a2 = __shfl((int)P2, sA);           \
    unsigned int b0 = __shfl((int)P1, sA), b2 = __shfl((int)P3, sA);           \
    unsigned int c0 = __shfl((int)P0, sB), c2 = __shfl((int)P2, sB);           \
    unsigned int d0 = __shfl((int)P1, sB), d2 = __shfl((int)P3, sB);           \
    union { unsigned int u[4]; short8 v; } pb_;                                \
    pb_.u[0] = hi ? a2 : a0; pb_.u[1] = hi ? b2 : b0;                          \
    pb_.u[2] = hi ? c2 : c0; pb_.u[3] = hi ? d2 : d0;                          \
    PA = pb_.v; }

#define NBAR()                                                                 \
    __builtin_amdgcn_sched_barrier(0);                                         \
    __builtin_amdgcn_s_barrier();                                              \
    __builtin_amdgcn_sched_barrier(0);

#define BAR()                                                                  \
    asm volatile("s_waitcnt lgkmcnt(0)" ::: "memory");                         \
    NBAR()

// one K-tile: glds K(t+1)->other buf | V(t) direct-global (transposed image) |
// mask(t) | QK (swizzled ds_read) | softmax | PV | one raw barrier
#define BODY_BF(BUFIMM, OTHERIMM, KT)                                          \
  { const int ktn = ((KT) < NKT - 1) ? (KT) + 1 : (KT);                        \
    const unsigned char* gK = wsKb + (size_t)ktn * KIMG + tid * 16;            \
    GLDS(gK,        smem + (OTHERIMM) + (wid << 10));                          \
    GLDS(gK + 4096, smem + (OTHERIMM) + (wid << 10) + 4096);                   \
    short8 vv0 = *(const short8*)(sv + vs0);                                   \
    short8 vv1 = *(const short8*)(sv + vs1);                                   \
    short8 vv2 = *(const short8*)(sv + vs2);                                   \
    short8 vv3 = *(const short8*)(sv + vs3);                                   \
    short8 vv4 = *(const short8*)(sv + vs4);                                   \
    short8 vv5 = *(const short8*)(sv + vs5);                                   \
    short8 vv6 = *(const short8*)(sv + vs6);                                   \
    short8 vv7 = *(const short8*)(sv + vs7);                                   \
    float4 mc0 = *(const float4*)(mq0 + (KT) * KBLK);                          \
    float4 mc1 = *(const float4*)(mq0 + (KT) * KBLK + 16);                     \
    f32x4 s00 = {0,0,0,0}, s01 = {0,0,0,0};                                    \
    __builtin_amdgcn_s_setprio(1);                                             \
    _Pragma("unroll")                                                          \
    for (int ks = 0; ks < 4; ++ks) {                                           \
      short8 ka0 = *(const short8*)(smem + (BUFIMM) + kaddr[ks]);              \
      short8 ka1 = *(const short8*)(smem + (BUFIMM) + 4096 + kaddr[ks]);       \
      s00 = __builtin_amdgcn_mfma_f32_16x16x32_bf16(ka0, qf[ks], s00, 0,0,0);  \
      s01 = __builtin_amdgcn_mfma_f32_16x16x32_bf16(ka1, qf[ks], s01, 0,0,0);  \
    }                                                                          \
    __builtin_amdgcn_s_setprio(0);                                             \
    short8 pa;                                                                 \
    SOFTMAX_PACK(pa, s00, s01, mc0, mc1, lp)                                   \
    __builtin_amdgcn_s_setprio(1);                                             \
    o[0] = __builtin_amdgcn_mfma_f32_16x16x32_bf16(pa, vv0, o[0], 0,0,0);      \
    o[1] = __builtin_amdgcn_mfma_f32_16x16x32_bf16(pa, vv1, o[1], 0,0,0);      \
    o[2] = __builtin_amdgcn_mfma_f32_16x16x32_bf16(pa, vv2, o[2], 0,0,0);      \
    o[3] = __builtin_amdgcn_mfma_f32_16x16x32_bf16(pa, vv3, o[3], 0,0,0);      \
    o[4] = __builtin_amdgcn_mfma_f32_16x16x32_bf16(pa, vv4, o[4], 0,0,0);      \
    o[5] = __builtin_amdgcn_mfma_f32_16x16x32_bf16(pa, vv5, o[5], 0,0,0);      \
    o[6] = __builtin_amdgcn_mfma_f32_16x16x32_bf16(pa, vv6, o[6], 0,0,0);      \
    o[7] = __builtin_amdgcn_mfma_f32_16x16x32_bf16(pa, vv7, o[7], 0,0,0);      \
    __builtin_amdgcn_s_setprio(0);                                             \
    sv += 64;                                                                  \
    NBAR() }

#define KERNEL_PRE(SMEMSZ)                                                     \
    __shared__ __align__(16) unsigned char smem[SMEMSZ];                       \
    const int tid  = threadIdx.x;                                              \
    const int lane = tid & 63, wid = tid >> 6;                                 \
    const int c = lane & 15, g = lane >> 4;                                    \
    const int bid = blockIdx.x;                                                \
    const int swz = (bid & 7) * 128 + (bid >> 3);  /* 1024 = 128 x 8, bijective */\
    const int bh = swz >> 5;                                                   \
    const int qb = swz & 31;                                                   \
    const float* x1b = x1 + ((size_t)bh * SQ + (size_t)qb * QBLK) * DD;        \
    const float* mb  = mask + ((size_t)bh * SQ + (size_t)qb * QBLK) * SK;      \
    float*      outb = out + ((size_t)bh * SQ + (size_t)qb * QBLK) * DD;       \
    const int sA = c + ((g & 1) << 5);                                         \
    const int sB = sA + 16;                                                    \
    const bool hi = (g >= 2);                                                  \
    const float* mq0 = mb + (size_t)(wid*16 + c) * SK + 4*g;

#define KERNEL_QLOAD()                                                         \
    short8 qf[4];                                                              \
    {  const float* q0r = x1b + (size_t)(wid*16 + c) * DD;                     \
       _Pragma("unroll")                                                       \
       for (int ks = 0; ks < 4; ++ks) {                                        \
           float4 a = *(const float4*)(q0r + ks*32 + 8*g);                     \
           float4 b = *(const float4*)(q0r + ks*32 + 8*g + 4);                 \
           union { unsigned int u[4]; short8 s; } t;                           \
           t.u[0]=pk_bf16(a.x,a.y); t.u[1]=pk_bf16(a.z,a.w);                   \
           t.u[2]=pk_bf16(b.x,b.y); t.u[3]=pk_bf16(b.z,b.w);                   \
           qf[ks]=t.s;                                                         \
       } }

#define KERNEL_EPILOGUE()                                                      \
    float l = lp; l += __shfl_xor(l, 16); l += __shfl_xor(l, 32);              \
    float il0 = 1.0f/__shfl(l, 4*g+0), il1 = 1.0f/__shfl(l, 4*g+1);            \
    float il2 = 1.0f/__shfl(l, 4*g+2), il3 = 1.0f/__shfl(l, 4*g+3);            \
    float* orow = outb + (size_t)(wid*16) * DD;                                \
    _Pragma("unroll")                                                          \
    for (int d8 = 0; d8 < 8; ++d8) {                                           \
        orow[(4*g + 0) * DD + d8*16 + c] = o[d8][0] * il0;                     \
        orow[(4*g + 1) * DD + d8*16 + c] = o[d8][1] * il1;                     \
        orow[(4*g + 2) * DD + d8*16 + c] = o[d8][2] * il2;                     \
        orow[(4*g + 3) * DD + d8*16 + c] = o[d8][3] * il3;                     \
    }

// ---- prepass A: swizzled K-image. image[r][ (A(d) ^ 16*(r&7)) + 2*(d&7) ] = bf16(x2[k][d])
// A(d) = 64*(d>>5) + 16*((d>>3)&3). Stored per (bh, 32-k tile) in glds load order.
__global__ __launch_bounds__(256) void prep_k(const float* __restrict__ x2,
                                              unsigned char* __restrict__ wsK) {
    const int blk = blockIdx.x;          // 32 bh x 64 tiles
    const int bh = blk >> 6, kt = blk & 63;
    const int t = threadIdx.x;
    const int r = t >> 3, dc = t & 7;
    const float* src = x2 + ((size_t)bh * SK + (size_t)(kt * 32 + r)) * DD + dc * 16;
    float4 a0 = *(const float4*)(src);
    float4 a1 = *(const float4*)(src + 4);
    float4 a2 = *(const float4*)(src + 8);
    float4 a3 = *(const float4*)(src + 12);
    u32x4 w0, w1;
    w0[0]=pk_bf16(a0.x,a0.y); w0[1]=pk_bf16(a0.z,a0.w);
    w0[2]=pk_bf16(a1.x,a1.y); w0[3]=pk_bf16(a1.z,a1.w);
    w1[0]=pk_bf16(a2.x,a2.y); w1[1]=pk_bf16(a2.z,a2.w);
    w1[2]=pk_bf16(a3.x,a3.y); w1[3]=pk_bf16(a3.z,a3.w);
    const int A0 = 64*(dc>>1) + 16*((2*dc)   & 3);
    const int A1 = 64*(dc>>1) + 16*((2*dc+1) & 3);
    const int keyr = 16 * (r & 7);
    unsigned char* dst = wsK + ((size_t)bh*64 + kt) * KIMG + r * 256;
    *(u32x4*)(dst + (A0 ^ keyr)) = w0;
    *(u32x4*)(dst + (A1 ^ keyr)) = w1;
}

// ---- prepass B: x2^T bf16: wsT[(bh*128 + d)*SK + k] = bf16(x2[bh][k][d])
#define PT 72
__global__ __launch_bounds__(256) void prep_t(const float* __restrict__ x2,
                                              unsigned short* __restrict__ wsT) {
    __shared__ unsigned short lt[128 * PT];
    const int blk = blockIdx.x;          // 32 bh x 32 chunks of 64 k
    const int bh = blk >> 5, kc = blk & 31;
    const int t = threadIdx.x;
    const float* src = x2 + ((size_t)bh * SK + (size_t)kc * 64) * DD;
#pragma unroll
    for (int i = 0; i < 8; ++i) {
        int idx = t + 256 * i;
        int row = idx >> 5, c4 = (idx & 31) * 4;
        float4 v = *(const float4*)(src + (size_t)row * DD + c4);
        lt[(c4+0)*PT + row] = f2bf(v.x);
        lt[(c4+1)*PT + row] = f2bf(v.y);
        lt[(c4+2)*PT + row] = f2bf(v.z);
        lt[(c4+3)*PT + row] = f2bf(v.w);
    }
    __syncthreads();
    const int d = t >> 1, kh = t & 1;
    const unsigned short* s = lt + d * PT + kh * 32;   // byte off d*144+kh*64: 16-aligned
    u32x4 u0 = *(const u32x4*)(s);
    u32x4 u1 = *(const u32x4*)(s + 8);
    u32x4 u2 = *(const u32x4*)(s + 16);
    u32x4 u3 = *(const u32x4*)(s + 24);
    unsigned short* dst = wsT + ((size_t)bh * DD + d) * SK + kc * 64 + kh * 32;
    *(u32x4*)(dst)      = u0;
    *(u32x4*)(dst + 8)  = u1;
    *(u32x4*)(dst + 16) = u2;
    *(u32x4*)(dst + 24) = u3;
}

__global__ __launch_bounds__(256, 4) void fattn_bf16(
    const float* __restrict__ x1, const unsigned char* __restrict__ wsK,
    const unsigned char* __restrict__ wsT,
    const float* __restrict__ mask, float* __restrict__ out)
{
    KERNEL_PRE(SMEM_BF)
    const unsigned char* wsKb = wsK + (size_t)bh * 64 * KIMG;
    const unsigned char* sv   = wsT + (size_t)bh * DD * SK * 2;
    // QK swizzled LDS read addresses (constant all tiles; row c+16 via +4096 imm)
    const int key = 16 * (c & 7);
    int kaddr[4];
#pragma unroll
    for (int ks = 0; ks < 4; ++ks)
        kaddr[ks] = c * 256 + ((ks * 64 + 16 * g) ^ key);
    // V fragment per-lane offsets (constant; sv advances 64 B/tile)
    const int vs0 = ((0*16 + c) * SK + 8*g) * 2;
    const int vs1 = ((1*16 + c) * SK + 8*g) * 2;
    const int vs2 = ((2*16 + c) * SK + 8*g) * 2;
    const int vs3 = ((3*16 + c) * SK + 8*g) * 2;
    const int vs4 = ((4*16 + c) * SK + 8*g) * 2;
    const int vs5 = ((5*16 + c) * SK + 8*g) * 2;
    const int vs6 = ((6*16 + c) * SK + 8*g) * 2;
    const int vs7 = ((7*16 + c) * SK + 8*g) * 2;

    // prologue: stage K(0) via glds; Q fragments from global f32
    GLDS(wsKb + tid * 16,        smem + (wid << 10));
    GLDS(wsKb + 4096 + tid * 16, smem + (wid << 10) + 4096);
    KERNEL_QLOAD()
    asm volatile("s_waitcnt vmcnt(0)" ::: "memory");
    NBAR()

    f32x4 o[8] = {};
    float lp = 0.f;

    for (int kt2 = 0; kt2 < NKT / 2; ++kt2) {
        BODY_BF(0,    KIMG, 2*kt2)
        BODY_BF(KIMG, 0,    2*kt2 + 1)
    }
    KERNEL_EPILOGUE()
}

// -------- fp32 fallback (R9-proven kernel, unchanged) --------
#define BODY_F32(KC0,KC1,KC2,KC3, VC0,VC1,VC2,VC3, MC0,MC1,                    \
                 KN0,KN1,KN2,KN3, VN0,VN1,VN2,VN3, MN0,MN1, KT)                \
  { const int kbn = ((KT) < NKT - 1) ? ((KT) + 1) * KBLK : (KT) * KBLK;        \
    KN0 = *(const float4*)(x2fb + (size_t)(kbn + kkf)      * DD + kd0);        \
    KN1 = *(const float4*)(x2fb + (size_t)(kbn + kkf)      * DD + kd0 + 4);    \
    KN2 = *(const float4*)(x2fb + (size_t)(kbn + kkf + 16) * DD + kd0);        \
    KN3 = *(const float4*)(x2fb + (size_t)(kbn + kkf + 16) * DD + kd0 + 4);    \
    VN0 = *(const float4*)(x2fb + (size_t)(kbn + 2*kp)     * DD + vdb);        \
    VN1 = *(const float4*)(x2fb + (size_t)(kbn + 2*kp)     * DD + vdb + 4);    \
    VN2 = *(const float4*)(x2fb + (size_t)(kbn + 2*kp + 1) * DD + vdb);        \
    VN3 = *(const float4*)(x2fb + (size_t)(kbn + 2*kp + 1) * DD + vdb + 4);    \
    MN0 = *(const float4*)(mq0 + kbn);                                         \
    MN1 = *(const float4*)(mq0 + kbn + 16);                                    \
    { union { unsigned int u[4]; short8 s; } k0_, k1_;                         \
      k0_.u[0]=pk_bf16(KC0.x,KC0.y); k0_.u[1]=pk_bf16(KC0.z,KC0.w);            \
      k0_.u[2]=pk_bf16(KC1.x,KC1.y); k0_.u[3]=pk_bf16(KC1.z,KC1.w);            \
      k1_.u[0]=pk_bf16(KC2.x,KC2.y); k1_.u[1]=pk_bf16(KC2.z,KC2.w);            \
      k1_.u[2]=pk_bf16(KC3.x,KC3.y); k1_.u[3]=pk_bf16(KC3.z,KC3.w);            \
      *(short8*)(smem + (kkf)      * KPITCH + 2*kd0) = k0_.s;                  \
      *(short8*)(smem + (kkf + 16) * KPITCH + 2*kd0) = k1_.s; }                \
    *(unsigned int*)(smem + VOFF_F + (vdb+0)*VPITCH + 4*kp) = pk_bf16(VC0.x, VC2.x); \
    *(unsigned int*)(smem + VOFF_F + (vdb+1)*VPITCH + 4*kp) = pk_bf16(VC0.y, VC2.y); \
    *(unsigned int*)(smem + VOFF_F + (vdb+2)*VPITCH + 4*kp) = pk_bf16(VC0.z, VC2.z); \
    *(unsigned int*)(smem + VOFF_F + (vdb+3)*VPITCH + 4*kp) = pk_bf16(VC0.w, VC2.w); \
    *(unsigned int*)(smem + VOFF_F + (vdb+4)*VPITCH + 4*kp) = pk_bf16(VC1.x, VC3.x); \
    *(unsigned int*)(smem + VOFF_F + (vdb+5)*VPITCH + 4*kp) = pk_bf16(VC1.y, VC3.y); \
    *(unsigned int*)(smem + VOFF_F + (vdb+6)*VPITCH + 4*kp) = pk_bf16(VC1.z, VC3.z); \
    *(unsigned int*)(smem + VOFF_F + (vdb+7)*VPITCH + 4*kp) = pk_bf16(VC1.w, VC3.w); \
    BAR()                                                                      \
    f32x4 s00={0,0,0,0}, s01={0,0,0,0};                                        \
    _Pragma("unroll")                                                          \
    for (int ks = 0; ks < 4; ++ks) {                                           \
      short8 ka0 = *(const short8*)(smem + (c)      * KPITCH + ks*64 + 16*g);  \
      short8 ka1 = *(const short8*)(smem + (16 + c) * KPITCH + ks*64 + 16*g);  \
      s00 = __builtin_amdgcn_mfma_f32_16x16x32_bf16(ka0, qf[ks], s00, 0,0,0);  \
      s01 = __builtin_amdgcn_mfma_f32_16x16x32_bf16(ka1, qf[ks], s01, 0,0,0);  \
    }                                                                          \
    short8 pa;                                                                 \
    SOFTMAX_PACK(pa, s00, s01, MC0, MC1, lp)                                   \
    _Pragma("unroll")                                                          \
    for (int d8 = 0; d8 < 8; ++d8) {                                           \
      short8 vv = *(const short8*)(smem + VOFF_F + (d8*16 + c)*VPITCH + 16*g); \
      o[d8] = __builtin_amdgcn_mfma_f32_16x16x32_bf16(pa, vv, o[d8], 0,0,0);   \
    }                                                                          \
    BAR()                                                                      \
  }

__global__ __launch_bounds__(256, 3) void fattn_f32(
    const float* __restrict__ x1, const float* __restrict__ x2,
    const float* __restrict__ mask, float* __restrict__ out)
{
    KERNEL_PRE(SMEM_F32)
    const float* x2fb = x2 + (size_t)bh * SK * DD;
    const int kkf = tid >> 4, kd0 = (tid & 15) * 8;
    const int kp  = tid & 15, vdb = (tid >> 4) * 8;

    float4 kA0 = *(const float4*)(x2fb + (size_t)(kkf)      * DD + kd0);
    float4 kA1 = *(const float4*)(x2fb + (size_t)(kkf)      * DD + kd0 + 4);
    float4 kA2 = *(const float4*)(x2fb + (size_t)(kkf + 16) * DD + kd0);
    float4 kA3 = *(const float4*)(x2fb + (size_t)(kkf + 16) * DD + kd0 + 4);
    float4 vA0 = *(const float4*)(x2fb + (size_t)(2*kp)     * DD + vdb);
    float4 vA1 = *(const float4*)(x2fb + (size_t)(2*kp)     * DD + vdb + 4);
    float4 vA2 = *(const float4*)(x2fb + (size_t)(2*kp + 1) * DD + vdb);
    float4 vA3 = *(const float4*)(x2fb + (size_t)(2*kp + 1) * DD + vdb + 4);
    float4 mA0 = *(const float4*)(mq0);
    float4 mA1 = *(const float4*)(mq0 + 16);
    float4 kB0,kB1,kB2,kB3, vB0,vB1,vB2,vB3, mB0,mB1;

    KERNEL_QLOAD()

    f32x4 o[8] = {};
    float lp = 0.f;

    for (int kt2 = 0; kt2 < NKT / 2; ++kt2) {
        BODY_F32(kA0,kA1,kA2,kA3, vA0,vA1,vA2,vA3, mA0,mA1,
                 kB0,kB1,kB2,kB3, vB0,vB1,vB2,vB3, mB0,mB1, 2*kt2)
        BODY_F32(kB0,kB1,kB2,kB3, vB0,vB1,vB2,vB3, mB0,mB1,
                 kA0,kA1,kA2,kA3, vA0,vA1,vA2,vA3, mA0,mA1, 2*kt2 + 1)
    }
    KERNEL_EPILOGUE()
}

extern "C" void kernel_launch(void* const* d_in, const int* in_sizes, int n_in,
                              void* d_out, int out_size, void* d_ws, size_t ws_size,
                              hipStream_t stream) {
    const float* x1   = (const float*)d_in[0];
    const float* x2   = (const float*)d_in[1];
    const float* mask = (const float*)d_in[2];
    float* out = (float*)d_out;
    const size_t szK = (size_t)NBH * 64 * KIMG;            // 16.78 MB
    const size_t szT = (size_t)NBH * DD * SK * 2;          // 16.78 MB
    if (ws_size >= szK + szT) {
        unsigned char* wsK = (unsigned char*)d_ws;
        unsigned short* wsT = (unsigned short*)(wsK + szK);
        prep_k<<<dim3(NBH * 64), dim3(256), 0, stream>>>(x2, wsK);
        prep_t<<<dim3(NBH * 32), dim3(256), 0, stream>>>(x2, wsT);
        fattn_bf16<<<dim3(NBH * (SQ / QBLK)), dim3(256), 0, stream>>>(
            x1, wsK, (const unsigned char*)wsT, mask, out);
    } else {
        fattn_f32<<<dim3(NBH * (SQ / QBLK)), dim3(256), 0, stream>>>(x1, x2, mask, out);
    }
}

// Round 12
// 190.506 us; speedup vs baseline: 4.3619x; 4.3619x over previous
//
#include <hip/hip_runtime.h>
#include <hip/hip_bf16.h>

#define SQ 2048
#define SK 2048
#define DD 128
#define NBH 32
#define QBLK 64
#define KBLK 32
#define NKT (SK / KBLK)
#define SCALE 0.20884964425119185f
#define SCL2 (SCALE * 1.4426950408889634f)   // fold log2(e): exp2

typedef __attribute__((ext_vector_type(8))) short short8;
typedef __attribute__((ext_vector_type(4))) float f32x4;
typedef __attribute__((ext_vector_type(4))) unsigned int u32x4;

// bf16 path LDS: K-image dbuf (2x8KB) at 0, V-image dbuf (2x8KB) at 16384
#define KIMG 8192
#define SMEM_BF 32768
// f32 fallback LDS (R9-proven layout)
#define KPITCH 272
#define VPITCH 80
#define VOFF_F 8704
#define SMEM_F32 18944

#define GLDS(G, L) __builtin_amdgcn_global_load_lds( \
    (const __attribute__((address_space(1))) unsigned int*)(G), \
    (__attribute__((address_space(3))) unsigned int*)(L), 16, 0, 0)

static __device__ __forceinline__ unsigned int pk_bf16(float lo, float hi) {
    float2 f2; f2.x = lo; f2.y = hi;
    __hip_bfloat162 h = __float22bfloat162_rn(f2);   // v_cvt_pk_bf16_f32
    union { __hip_bfloat162 h2; unsigned int u; } cv; cv.h2 = h;
    return cv.u;
}

// natural-order softmax: P feeds PV A-operand directly (k-permutation baked
// into the V image; MFMA k-sum is permutation-invariant)
#define SOFTMAX_NAT(PA, SA_, SB_, MCa, MCb, LPART)                             \
  { float p_[8];                                                               \
    p_[0] = __builtin_amdgcn_exp2f(SA_[0]*SCL2);                               \
    p_[1] = __builtin_amdgcn_exp2f(SA_[1]*SCL2);                               \
    p_[2] = __builtin_amdgcn_exp2f(SA_[2]*SCL2);                               \
    p_[3] = __builtin_amdgcn_exp2f(SA_[3]*SCL2);                               \
    p_[4] = __builtin_amdgcn_exp2f(SB_[0]*SCL2);                               \
    p_[5] = __builtin_amdgcn_exp2f(SB_[1]*SCL2);                               \
    p_[6] = __builtin_amdgcn_exp2f(SB_[2]*SCL2);                               \
    p_[7] = __builtin_amdgcn_exp2f(SB_[3]*SCL2);                               \
    LPART += ((p_[0]+p_[1]) + (p_[2]+p_[3])) + ((p_[4]+p_[5]) + (p_[6]+p_[7]));\
    p_[0]*=MCa.x; p_[1]*=MCa.y; p_[2]*=MCa.z; p_[3]*=MCa.w;                    \
    p_[4]*=MCb.x; p_[5]*=MCb.y; p_[6]*=MCb.z; p_[7]*=MCb.w;                    \
    union { unsigned int u[4]; short8 v; } pb_;                                \
    pb_.u[0] = pk_bf16(p_[0],p_[1]); pb_.u[1] = pk_bf16(p_[2],p_[3]);          \
    pb_.u[2] = pk_bf16(p_[4],p_[5]); pb_.u[3] = pk_bf16(p_[6],p_[7]);          \
    PA = pb_.v; }

// f32 fallback keeps the shfl-redistribution (R3..R9-proven)
#define SOFTMAX_PACK(PA, SA_, SB_, MCa, MCb, LPART)                            \
  { float p_[8];                                                               \
    p_[0] = __builtin_amdgcn_exp2f(SA_[0]*SCL2);                               \
    p_[1] = __builtin_amdgcn_exp2f(SA_[1]*SCL2);                               \
    p_[2] = __builtin_amdgcn_exp2f(SA_[2]*SCL2);                               \
    p_[3] = __builtin_amdgcn_exp2f(SA_[3]*SCL2);                               \
    p_[4] = __builtin_amdgcn_exp2f(SB_[0]*SCL2);                               \
    p_[5] = __builtin_amdgcn_exp2f(SB_[1]*SCL2);                               \
    p_[6] = __builtin_amdgcn_exp2f(SB_[2]*SCL2);                               \
    p_[7] = __builtin_amdgcn_exp2f(SB_[3]*SCL2);                               \
    LPART += ((p_[0]+p_[1]) + (p_[2]+p_[3])) + ((p_[4]+p_[5]) + (p_[6]+p_[7]));\
    p_[0]*=MCa.x; p_[1]*=MCa.y; p_[2]*=MCa.z; p_[3]*=MCa.w;                    \
    p_[4]*=MCb.x; p_[5]*=MCb.y; p_[6]*=MCb.z; p_[7]*=MCb.w;                    \
    unsigned int P0 = pk_bf16(p_[0],p_[1]), P1 = pk_bf16(p_[2],p_[3]);         \
    unsigned int P2 = pk_bf16(p_[4],p_[5]), P3 = pk_bf16(p_[6],p_[7]);         \
    unsigned int a0 = __shfl((int)P0, sA), a2 = __shfl((int)P2, sA);           \
    unsigned int b0 = __shfl((int)P1, sA), b2 = __shfl((int)P3, sA);           \
    unsigned int c0 = __shfl((int)P0, sB), c2 = __shfl((int)P2, sB);           \
    unsigned int d0 = __shfl((int)P1, sB), d2 = __shfl((int)P3, sB);           \
    union { unsigned int u[4]; short8 v; } pb_;                                \
    pb_.u[0] = hi ? a2 : a0; pb_.u[1] = hi ? b2 : b0;                          \
    pb_.u[2] = hi ? c2 : c0; pb_.u[3] = hi ? d2 : d0;                          \
    PA = pb_.v; }

#define BAR()                                                                  \
    asm volatile("s_waitcnt lgkmcnt(0)" ::: "memory");                         \
    __builtin_amdgcn_sched_barrier(0);                                         \
    __builtin_amdgcn_s_barrier();                                              \
    __builtin_amdgcn_sched_barrier(0);

#define VBAR()                                                                 \
    asm volatile("s_waitcnt vmcnt(0)" ::: "memory");                           \
    __builtin_amdgcn_sched_barrier(0);                                         \
    __builtin_amdgcn_s_barrier();                                              \
    __builtin_amdgcn_sched_barrier(0);

// one K-tile: glds K/V(t+1)->other buf + mask(t+1) | QK | softmax | PV |
// vmcnt(0) + one raw barrier
#define BODY_BF(CUR, OTH, MC0, MC1, MN0, MN1, KT)                              \
  { const int ktn = ((KT) < NKT - 1) ? (KT) + 1 : (KT);                        \
    const unsigned char* gK = wsKb + (size_t)ktn * KIMG + tid * 16;            \
    const unsigned char* gV = wsVb + (size_t)ktn * KIMG + tid * 16;            \
    GLDS(gK,        smem + (OTH)*KIMG + (wid << 10));                          \
    GLDS(gK + 4096, smem + (OTH)*KIMG + 4096 + (wid << 10));                   \
    GLDS(gV,        smem + 16384 + (OTH)*KIMG + (wid << 10));                  \
    GLDS(gV + 4096, smem + 16384 + (OTH)*KIMG + 4096 + (wid << 10));           \
    MN0 = *(const float4*)(mq0 + ktn * KBLK);                                  \
    MN1 = *(const float4*)(mq0 + ktn * KBLK + 16);                             \
    f32x4 s00 = {0,0,0,0}, s01 = {0,0,0,0};                                    \
    __builtin_amdgcn_s_setprio(1);                                             \
    _Pragma("unroll")                                                          \
    for (int ks = 0; ks < 4; ++ks) {                                           \
      short8 ka0 = *(const short8*)(smem + (CUR)*KIMG + kaddr[ks]);            \
      short8 ka1 = *(const short8*)(smem + (CUR)*KIMG + 4096 + kaddr[ks]);     \
      s00 = __builtin_amdgcn_mfma_f32_16x16x32_bf16(ka0, qf[ks], s00, 0,0,0);  \
      s01 = __builtin_amdgcn_mfma_f32_16x16x32_bf16(ka1, qf[ks], s01, 0,0,0);  \
    }                                                                          \
    __builtin_amdgcn_s_setprio(0);                                             \
    short8 pa;                                                                 \
    SOFTMAX_NAT(pa, s00, s01, MC0, MC1, lp)                                    \
    __builtin_amdgcn_s_setprio(1);                                             \
    _Pragma("unroll")                                                          \
    for (int d8 = 0; d8 < 8; ++d8) {                                           \
      short8 vv = *(const short8*)(smem + 16384 + (CUR)*KIMG                   \
                                   + (d8*16 + c)*64 + 16*g);                   \
      o[d8] = __builtin_amdgcn_mfma_f32_16x16x32_bf16(pa, vv, o[d8], 0,0,0);   \
    }                                                                          \
    __builtin_amdgcn_s_setprio(0);                                             \
    VBAR() }

#define KERNEL_PRE(SMEMSZ)                                                     \
    __shared__ __align__(16) unsigned char smem[SMEMSZ];                       \
    const int tid  = threadIdx.x;                                              \
    const int lane = tid & 63, wid = tid >> 6;                                 \
    const int c = lane & 15, g = lane >> 4;                                    \
    const int bid = blockIdx.x;                                                \
    const int swz = (bid & 7) * 128 + (bid >> 3);  /* 1024 = 128 x 8, bijective */\
    const int bh = swz >> 5;                                                   \
    const int qb = swz & 31;                                                   \
    const float* x1b = x1 + ((size_t)bh * SQ + (size_t)qb * QBLK) * DD;        \
    const float* mb  = mask + ((size_t)bh * SQ + (size_t)qb * QBLK) * SK;      \
    float*      outb = out + ((size_t)bh * SQ + (size_t)qb * QBLK) * DD;       \
    const int sA = c + ((g & 1) << 5);                                         \
    const int sB = sA + 16;                                                    \
    const bool hi = (g >= 2);                                                  \
    const float* mq0 = mb + (size_t)(wid*16 + c) * SK + 4*g;

#define KERNEL_QLOAD()                                                         \
    short8 qf[4];                                                              \
    {  const float* q0r = x1b + (size_t)(wid*16 + c) * DD;                     \
       _Pragma("unroll")                                                       \
       for (int ks = 0; ks < 4; ++ks) {                                        \
           float4 a = *(const float4*)(q0r + ks*32 + 8*g);                     \
           float4 b = *(const float4*)(q0r + ks*32 + 8*g + 4);                 \
           union { unsigned int u[4]; short8 s; } t;                           \
           t.u[0]=pk_bf16(a.x,a.y); t.u[1]=pk_bf16(a.z,a.w);                   \
           t.u[2]=pk_bf16(b.x,b.y); t.u[3]=pk_bf16(b.z,b.w);                   \
           qf[ks]=t.s;                                                         \
       } }

#define KERNEL_EPILOGUE()                                                      \
    float l = lp; l += __shfl_xor(l, 16); l += __shfl_xor(l, 32);              \
    float il0 = 1.0f/__shfl(l, 4*g+0), il1 = 1.0f/__shfl(l, 4*g+1);            \
    float il2 = 1.0f/__shfl(l, 4*g+2), il3 = 1.0f/__shfl(l, 4*g+3);            \
    float* orow = outb + (size_t)(wid*16) * DD;                                \
    _Pragma("unroll")                                                          \
    for (int d8 = 0; d8 < 8; ++d8) {                                           \
        orow[(4*g + 0) * DD + d8*16 + c] = o[d8][0] * il0;                     \
        orow[(4*g + 1) * DD + d8*16 + c] = o[d8][1] * il1;                     \
        orow[(4*g + 2) * DD + d8*16 + c] = o[d8][2] * il2;                     \
        orow[(4*g + 3) * DD + d8*16 + c] = o[d8][3] * il3;                     \
    }

// ---- fused prepass: K-image (R11-verified swizzle) + V-image (d-major,
// k->slot permuted s = 8*(tt>>2) + 4*(k>>4) + (tt&3), tt=k&15) ----
__global__ __launch_bounds__(256) void prep_kv(const float* __restrict__ x2,
                                               unsigned char* __restrict__ wsK,
                                               unsigned char* __restrict__ wsV) {
    __shared__ unsigned short lt[128 * 34];    // 8704 B, row stride 68 B
    const int blk = blockIdx.x;                // 32 bh x 64 tiles
    const int bh = blk >> 6, kt = blk & 63;
    const int t = threadIdx.x;
    const int r = t >> 3, dc = t & 7;          // k-row, 16-wide d-chunk
    const float* src = x2 + ((size_t)bh * SK + (size_t)(kt * 32 + r)) * DD + dc * 16;
    float4 a0 = *(const float4*)(src);
    float4 a1 = *(const float4*)(src + 4);
    float4 a2 = *(const float4*)(src + 8);
    float4 a3 = *(const float4*)(src + 12);
    u32x4 w0, w1;
    w0[0]=pk_bf16(a0.x,a0.y); w0[1]=pk_bf16(a0.z,a0.w);
    w0[2]=pk_bf16(a1.x,a1.y); w0[3]=pk_bf16(a1.z,a1.w);
    w1[0]=pk_bf16(a2.x,a2.y); w1[1]=pk_bf16(a2.z,a2.w);
    w1[2]=pk_bf16(a3.x,a3.y); w1[3]=pk_bf16(a3.z,a3.w);
    // K image
    const int A0 = 64*(dc>>1) + 16*((2*dc)   & 3);
    const int A1 = 64*(dc>>1) + 16*((2*dc+1) & 3);
    const int keyr = 16 * (r & 7);
    unsigned char* dstK = wsK + ((size_t)bh*64 + kt) * KIMG + r * 256;
    *(u32x4*)(dstK + (A0 ^ keyr)) = w0;
    *(u32x4*)(dstK + (A1 ^ keyr)) = w1;
    // V image via LDS transpose, permuted slot
    const int tt = r & 15;
    const int s = 8*(tt>>2) + 4*(r>>4) + (tt&3);
#pragma unroll
    for (int i = 0; i < 4; ++i) {
        unsigned int u = w0[i];
        lt[(dc*16 + 2*i    ) * 34 + s] = (unsigned short)(u & 0xffffu);
        lt[(dc*16 + 2*i + 1) * 34 + s] = (unsigned short)(u >> 16);
    }
#pragma unroll
    for (int i = 0; i < 4; ++i) {
        unsigned int u = w1[i];
        lt[(dc*16 + 8 + 2*i    ) * 34 + s] = (unsigned short)(u & 0xffffu);
        lt[(dc*16 + 8 + 2*i + 1) * 34 + s] = (unsigned short)(u >> 16);
    }
    __syncthreads();
    const int d = t >> 1, h = t & 1;
    const unsigned int* lrow = (const unsigned int*)((const unsigned char*)lt + d*68 + h*32);
    u32x4 o0, o1;
    o0[0]=lrow[0]; o0[1]=lrow[1]; o0[2]=lrow[2]; o0[3]=lrow[3];
    o1[0]=lrow[4]; o1[1]=lrow[5]; o1[2]=lrow[6]; o1[3]=lrow[7];
    unsigned char* dstV = wsV + ((size_t)bh*64 + kt) * KIMG + d*64 + h*32;
    *(u32x4*)(dstV)      = o0;
    *(u32x4*)(dstV + 16) = o1;
}

__global__ __launch_bounds__(256, 4) void fattn_bf16(
    const float* __restrict__ x1, const unsigned char* __restrict__ wsK,
    const unsigned char* __restrict__ wsV,
    const float* __restrict__ mask, float* __restrict__ out)
{
    KERNEL_PRE(SMEM_BF)
    const unsigned char* wsKb = wsK + (size_t)bh * 64 * KIMG;
    const unsigned char* wsVb = wsV + (size_t)bh * 64 * KIMG;
    // QK swizzled LDS read addresses (R11-verified; row c+16 via +4096)
    const int key = 16 * (c & 7);
    int kaddr[4];
#pragma unroll
    for (int ks = 0; ks < 4; ++ks)
        kaddr[ks] = c * 256 + ((ks * 64 + 16 * g) ^ key);

    // prologue: stage tile 0, load mask(0), Q fragments
    GLDS(wsKb + tid * 16,        smem + (wid << 10));
    GLDS(wsKb + 4096 + tid * 16, smem + 4096 + (wid << 10));
    GLDS(wsVb + tid * 16,        smem + 16384 + (wid << 10));
    GLDS(wsVb + 4096 + tid * 16, smem + 16384 + 4096 + (wid << 10));
    float4 mA0 = *(const float4*)(mq0);
    float4 mA1 = *(const float4*)(mq0 + 16);
    float4 mB0, mB1;
    KERNEL_QLOAD()
    VBAR()

    f32x4 o[8] = {};
    float lp = 0.f;

    for (int kt2 = 0; kt2 < NKT / 2; ++kt2) {
        BODY_BF(0, 1, mA0, mA1, mB0, mB1, 2*kt2)
        BODY_BF(1, 0, mB0, mB1, mA0, mA1, 2*kt2 + 1)
    }
    KERNEL_EPILOGUE()
}

// -------- fp32 fallback (R9-proven kernel, unchanged) --------
#define BODY_F32(KC0,KC1,KC2,KC3, VC0,VC1,VC2,VC3, MC0,MC1,                    \
                 KN0,KN1,KN2,KN3, VN0,VN1,VN2,VN3, MN0,MN1, KT)                \
  { const int kbn = ((KT) < NKT - 1) ? ((KT) + 1) * KBLK : (KT) * KBLK;        \
    KN0 = *(const float4*)(x2fb + (size_t)(kbn + kkf)      * DD + kd0);        \
    KN1 = *(const float4*)(x2fb + (size_t)(kbn + kkf)      * DD + kd0 + 4);    \
    KN2 = *(const float4*)(x2fb + (size_t)(kbn + kkf + 16) * DD + kd0);        \
    KN3 = *(const float4*)(x2fb + (size_t)(kbn + kkf + 16) * DD + kd0 + 4);    \
    VN0 = *(const float4*)(x2fb + (size_t)(kbn + 2*kp)     * DD + vdb);        \
    VN1 = *(const float4*)(x2fb + (size_t)(kbn + 2*kp)     * DD + vdb + 4);    \
    VN2 = *(const float4*)(x2fb + (size_t)(kbn + 2*kp + 1) * DD + vdb);        \
    VN3 = *(const float4*)(x2fb + (size_t)(kbn + 2*kp + 1) * DD + vdb + 4);    \
    MN0 = *(const float4*)(mq0 + kbn);                                         \
    MN1 = *(const float4*)(mq0 + kbn + 16);                                    \
    { union { unsigned int u[4]; short8 s; } k0_, k1_;                         \
      k0_.u[0]=pk_bf16(KC0.x,KC0.y); k0_.u[1]=pk_bf16(KC0.z,KC0.w);            \
      k0_.u[2]=pk_bf16(KC1.x,KC1.y); k0_.u[3]=pk_bf16(KC1.z,KC1.w);            \
      k1_.u[0]=pk_bf16(KC2.x,KC2.y); k1_.u[1]=pk_bf16(KC2.z,KC2.w);            \
      k1_.u[2]=pk_bf16(KC3.x,KC3.y); k1_.u[3]=pk_bf16(KC3.z,KC3.w);            \
      *(short8*)(smem + (kkf)      * KPITCH + 2*kd0) = k0_.s;                  \
      *(short8*)(smem + (kkf + 16) * KPITCH + 2*kd0) = k1_.s; }                \
    *(unsigned int*)(smem + VOFF_F + (vdb+0)*VPITCH + 4*kp) = pk_bf16(VC0.x, VC2.x); \
    *(unsigned int*)(smem + VOFF_F + (vdb+1)*VPITCH + 4*kp) = pk_bf16(VC0.y, VC2.y); \
    *(unsigned int*)(smem + VOFF_F + (vdb+2)*VPITCH + 4*kp) = pk_bf16(VC0.z, VC2.z); \
    *(unsigned int*)(smem + VOFF_F + (vdb+3)*VPITCH + 4*kp) = pk_bf16(VC0.w, VC2.w); \
    *(unsigned int*)(smem + VOFF_F + (vdb+4)*VPITCH + 4*kp) = pk_bf16(VC1.x, VC3.x); \
    *(unsigned int*)(smem + VOFF_F + (vdb+5)*VPITCH + 4*kp) = pk_bf16(VC1.y, VC3.y); \
    *(unsigned int*)(smem + VOFF_F + (vdb+6)*VPITCH + 4*kp) = pk_bf16(VC1.z, VC3.z); \
    *(unsigned int*)(smem + VOFF_F + (vdb+7)*VPITCH + 4*kp) = pk_bf16(VC1.w, VC3.w); \
    BAR()                                                                      \
    f32x4 s00={0,0,0,0}, s01={0,0,0,0};                                        \
    _Pragma("unroll")                                                          \
    for (int ks = 0; ks < 4; ++ks) {                                           \
      short8 ka0 = *(const short8*)(smem + (c)      * KPITCH + ks*64 + 16*g);  \
      short8 ka1 = *(const short8*)(smem + (16 + c) * KPITCH + ks*64 + 16*g);  \
      s00 = __builtin_amdgcn_mfma_f32_16x16x32_bf16(ka0, qf[ks], s00, 0,0,0);  \
      s01 = __builtin_amdgcn_mfma_f32_16x16x32_bf16(ka1, qf[ks], s01, 0,0,0);  \
    }                                                                          \
    short8 pa;                                                                 \
    SOFTMAX_PACK(pa, s00, s01, MC0, MC1, lp)                                   \
    _Pragma("unroll")                                                          \
    for (int d8 = 0; d8 < 8; ++d8) {                                           \
      short8 vv = *(const short8*)(smem + VOFF_F + (d8*16 + c)*VPITCH + 16*g); \
      o[d8] = __builtin_amdgcn_mfma_f32_16x16x32_bf16(pa, vv, o[d8], 0,0,0);   \
    }                                                                          \
    BAR()                                                                      \
  }

__global__ __launch_bounds__(256, 3) void fattn_f32(
    const float* __restrict__ x1, const float* __restrict__ x2,
    const float* __restrict__ mask, float* __restrict__ out)
{
    KERNEL_PRE(SMEM_F32)
    const float* x2fb = x2 + (size_t)bh * SK * DD;
    const int kkf = tid >> 4, kd0 = (tid & 15) * 8;
    const int kp  = tid & 15, vdb = (tid >> 4) * 8;

    float4 kA0 = *(const float4*)(x2fb + (size_t)(kkf)      * DD + kd0);
    float4 kA1 = *(const float4*)(x2fb + (size_t)(kkf)      * DD + kd0 + 4);
    float4 kA2 = *(const float4*)(x2fb + (size_t)(kkf + 16) * DD + kd0);
    float4 kA3 = *(const float4*)(x2fb + (size_t)(kkf + 16) * DD + kd0 + 4);
    float4 vA0 = *(const float4*)(x2fb + (size_t)(2*kp)     * DD + vdb);
    float4 vA1 = *(const float4*)(x2fb + (size_t)(2*kp)     * DD + vdb + 4);
    float4 vA2 = *(const float4*)(x2fb + (size_t)(2*kp + 1) * DD + vdb);
    float4 vA3 = *(const float4*)(x2fb + (size_t)(2*kp + 1) * DD + vdb + 4);
    float4 mA0 = *(const float4*)(mq0);
    float4 mA1 = *(const float4*)(mq0 + 16);
    float4 kB0,kB1,kB2,kB3, vB0,vB1,vB2,vB3, mB0,mB1;

    KERNEL_QLOAD()

    f32x4 o[8] = {};
    float lp = 0.f;

    for (int kt2 = 0; kt2 < NKT / 2; ++kt2) {
        BODY_F32(kA0,kA1,kA2,kA3, vA0,vA1,vA2,vA3, mA0,mA1,
                 kB0,kB1,kB2,kB3, vB0,vB1,vB2,vB3, mB0,mB1, 2*kt2)
        BODY_F32(kB0,kB1,kB2,kB3, vB0,vB1,vB2,vB3, mB0,mB1,
                 kA0,kA1,kA2,kA3, vA0,vA1,vA2,vA3, mA0,mA1, 2*kt2 + 1)
    }
    KERNEL_EPILOGUE()
}

extern "C" void kernel_launch(void* const* d_in, const int* in_sizes, int n_in,
                              void* d_out, int out_size, void* d_ws, size_t ws_size,
                              hipStream_t stream) {
    const float* x1   = (const float*)d_in[0];
    const float* x2   = (const float*)d_in[1];
    const float* mask = (const float*)d_in[2];
    float* out = (float*)d_out;
    const size_t szK = (size_t)NBH * 64 * KIMG;            // 16.78 MB
    const size_t szV = (size_t)NBH * 64 * KIMG;            // 16.78 MB
    if (ws_size >= szK + szV) {
        unsigned char* wsK = (unsigned char*)d_ws;
        unsigned char* wsV = wsK + szK;
        prep_kv<<<dim3(NBH * 64), dim3(256), 0, stream>>>(x2, wsK, wsV);
        fattn_bf16<<<dim3(NBH * (SQ / QBLK)), dim3(256), 0, stream>>>(
            x1, wsK, wsV, mask, out);
    } else {
        fattn_f32<<<dim3(NBH * (SQ / QBLK)), dim3(256), 0, stream>>>(x1, x2, mask, out);
    }
}